// Round 1
// baseline (1570.686 us; speedup 1.0000x reference)
//
#include <hip/hip_runtime.h>

// Problem constants
static constexpr int N_   = 100000;
static constexpr int E_   = 1600000;
static constexpr int FIN_ = 128;
static constexpr int DIM_ = 32;
static constexpr int NC_  = 40;

// ---------------------------------------------------------------------------
// 1. Edge dtype detection: reference declares int64, but under default JAX
//    config (x64 off) the array is int32. Interpreting an int32 buffer as
//    int64 yields values with random high words -> out of [0,N) with
//    overwhelming probability. flag=1 => int64 layout.
// ---------------------------------------------------------------------------
__global__ void detect_kernel(const void* __restrict__ edge, int* __restrict__ flag) {
    if (blockIdx.x == 0 && threadIdx.x == 0) {
        const long long* p = (const long long*)edge;
        int ok = 1;
        for (int i = 0; i < 64; ++i) {
            long long v = p[i];
            if (v < 0 || v >= (long long)N_) { ok = 0; break; }
        }
        *flag = ok;
    }
}

__global__ __launch_bounds__(256) void convert_kernel(const void* __restrict__ edge,
                                                      const int* __restrict__ flag,
                                                      int* __restrict__ out) {
    int i = blockIdx.x * 256 + threadIdx.x;
    if (i >= 2 * E_) return;
    int v = (*flag) ? (int)((const long long*)edge)[i] : ((const int*)edge)[i];
    out[i] = v;
}

// ---------------------------------------------------------------------------
// 2. y = x @ w1a   (100000x128 @ 128x32). 32 nodes per block, 256 threads.
// ---------------------------------------------------------------------------
__global__ __launch_bounds__(256) void proj1_kernel(const float* __restrict__ x,
                                                    const float* __restrict__ w,
                                                    float* __restrict__ y) {
    __shared__ float wsm[FIN_ * DIM_];   // w[k][d]
    __shared__ float xs[32][FIN_];       // 32 node rows
    int tid = threadIdx.x;

    const float4* w4 = (const float4*)w;
    float4* ws4 = (float4*)wsm;
    for (int i = tid; i < FIN_ * DIM_ / 4; i += 256) ws4[i] = w4[i];

    int nodeBase = blockIdx.x * 32;
    const float4* x4 = (const float4*)(x + (size_t)nodeBase * FIN_);
    float4* xs4 = (float4*)&xs[0][0];
    for (int i = tid; i < 32 * FIN_ / 4; i += 256) xs4[i] = x4[i];
    __syncthreads();

    int d = tid & 31, ns = tid >> 5;     // ns in [0,8)
    for (int rep = 0; rep < 4; ++rep) {
        int node = ns + rep * 8;
        float acc = 0.f;
#pragma unroll 4
        for (int k = 0; k < FIN_; ++k) acc += xs[node][k] * wsm[k * DIM_ + d];
        y[(size_t)(nodeBase + node) * DIM_ + d] = acc;
    }
}

// ---------------------------------------------------------------------------
// 3. Scatter-add aggregation: agg[dst] += vec[src], 8 lanes per edge.
// ---------------------------------------------------------------------------
__global__ __launch_bounds__(256) void agg_kernel(const int* __restrict__ src,
                                                  const int* __restrict__ dst,
                                                  const float* __restrict__ vec,
                                                  float* __restrict__ agg) {
    int t = blockIdx.x * 256 + threadIdx.x;
    int e = t >> 3;
    if (e >= E_) return;
    int j = (t & 7) * 4;
    int s  = src[e];
    int d2 = dst[e];
    const float4 v = *(const float4*)(vec + (size_t)s * DIM_ + j);
    float* p = agg + (size_t)d2 * DIM_ + j;
    unsafeAtomicAdd(p + 0, v.x);
    unsafeAtomicAdd(p + 1, v.y);
    unsafeAtomicAdd(p + 2, v.z);
    unsafeAtomicAdd(p + 3, v.w);
}

// ---------------------------------------------------------------------------
// 4. Node MLP 1: u=relu(agg+y+b1a); h=u@w1b+b1b; r=relu(h); hb=bn1(r);
//    z = hb @ w2a.   8 nodes x 32 dims per block.
// ---------------------------------------------------------------------------
__global__ __launch_bounds__(256) void mlp1_kernel(const float* __restrict__ y,
                                                   const float* __restrict__ agg,
                                                   const float* __restrict__ b1a,
                                                   const float* __restrict__ w1b,
                                                   const float* __restrict__ b1b,
                                                   const float* __restrict__ g1,
                                                   const float* __restrict__ be1,
                                                   const float* __restrict__ m1,
                                                   const float* __restrict__ v1,
                                                   const float* __restrict__ w2a,
                                                   float* __restrict__ z) {
    __shared__ float w1s[DIM_ * DIM_];
    __shared__ float w2s[DIM_ * DIM_];
    __shared__ float s[8][DIM_ + 1];
    int tid = threadIdx.x;
    for (int i = tid; i < DIM_ * DIM_; i += 256) { w1s[i] = w1b[i]; w2s[i] = w2a[i]; }

    int d = tid & 31, ns = tid >> 5;
    int node = blockIdx.x * 8 + ns;
    size_t base = (size_t)node * DIM_ + d;

    float sc1 = g1[d] * rsqrtf(v1[d] + 1e-5f);
    float sh1 = be1[d] - m1[d] * sc1;

    float u = fmaxf(agg[base] + y[base] + b1a[d], 0.f);
    s[ns][d] = u;
    __syncthreads();

    float acc = b1b[d];
#pragma unroll
    for (int k = 0; k < DIM_; ++k) acc += s[ns][k] * w1s[k * DIM_ + d];
    float hb = fmaxf(acc, 0.f) * sc1 + sh1;   // relu then bn1
    __syncthreads();
    s[ns][d] = hb;
    __syncthreads();

    float acc2 = 0.f;
#pragma unroll
    for (int k = 0; k < DIM_; ++k) acc2 += s[ns][k] * w2s[k * DIM_ + d];
    z[base] = acc2;
}

// ---------------------------------------------------------------------------
// 5. Node MLP 2 + head: u=relu(agg2+z+b2a); h2=u@w2b+b2b; hb=bn2(h2);
//    f=relu(hb@fc1w+fc1b); logits=f@fc2w+fc2b; out=log_softmax(logits).
// ---------------------------------------------------------------------------
__global__ __launch_bounds__(256) void mlp2_kernel(const float* __restrict__ z,
                                                   const float* __restrict__ agg,
                                                   const float* __restrict__ b2a,
                                                   const float* __restrict__ w2b,
                                                   const float* __restrict__ b2b,
                                                   const float* __restrict__ g2,
                                                   const float* __restrict__ be2,
                                                   const float* __restrict__ m2,
                                                   const float* __restrict__ v2,
                                                   const float* __restrict__ f1w,
                                                   const float* __restrict__ f1b,
                                                   const float* __restrict__ f2w,
                                                   const float* __restrict__ f2b,
                                                   float* __restrict__ out) {
    __shared__ float wA[DIM_ * DIM_];
    __shared__ float wB[DIM_ * DIM_];
    __shared__ float wC[DIM_ * NC_];
    __shared__ float s[8][DIM_ + 1];
    int tid = threadIdx.x;
    for (int i = tid; i < DIM_ * DIM_; i += 256) { wA[i] = w2b[i]; wB[i] = f1w[i]; }
    for (int i = tid; i < DIM_ * NC_; i += 256) wC[i] = f2w[i];

    int d = tid & 31, ns = tid >> 5;
    int node = blockIdx.x * 8 + ns;
    size_t base = (size_t)node * DIM_ + d;

    float sc2 = g2[d] * rsqrtf(v2[d] + 1e-5f);
    float sh2 = be2[d] - m2[d] * sc2;

    float u = fmaxf(agg[base] + z[base] + b2a[d], 0.f);
    s[ns][d] = u;
    __syncthreads();

    float acc = b2b[d];
#pragma unroll
    for (int k = 0; k < DIM_; ++k) acc += s[ns][k] * wA[k * DIM_ + d];
    float hb = acc * sc2 + sh2;               // bn2, NO relu between conv2 and bn2
    __syncthreads();
    s[ns][d] = hb;
    __syncthreads();

    float f = f1b[d];
#pragma unroll
    for (int k = 0; k < DIM_; ++k) f += s[ns][k] * wB[k * DIM_ + d];
    f = fmaxf(f, 0.f);
    __syncthreads();
    s[ns][d] = f;
    __syncthreads();

    // logits: 40 columns; thread d owns col d, and (duplicated 4x, only d<8
    // writes/contributes) col 32+(d&7) to avoid divergence in the loop.
    int c2 = 32 + (d & 7);
    float l0 = f2b[d];
    float l1 = f2b[c2];
#pragma unroll
    for (int k = 0; k < DIM_; ++k) {
        float fv = s[ns][k];
        l0 += fv * wC[k * NC_ + d];
        l1 += fv * wC[k * NC_ + c2];
    }

    // log_softmax over 40 values held by this node's 32-lane half-wave
    float mx = fmaxf(l0, l1);
#pragma unroll
    for (int off = 16; off; off >>= 1) mx = fmaxf(mx, __shfl_xor(mx, off));
    float se = __expf(l0 - mx) + ((d < 8) ? __expf(l1 - mx) : 0.f);
#pragma unroll
    for (int off = 16; off; off >>= 1) se += __shfl_xor(se, off);
    float lse = mx + __logf(se);

    out[(size_t)node * NC_ + d] = l0 - lse;
    if (d < 8) out[(size_t)node * NC_ + 32 + d] = l1 - lse;
}

// ---------------------------------------------------------------------------
extern "C" void kernel_launch(void* const* d_in, const int* in_sizes, int n_in,
                              void* d_out, int out_size, void* d_ws, size_t ws_size,
                              hipStream_t stream) {
    const float* x   = (const float*)d_in[0];
    const void*  edg = d_in[1];
    const float* w1a = (const float*)d_in[2];
    const float* b1a = (const float*)d_in[3];
    const float* w1b = (const float*)d_in[4];
    const float* b1b = (const float*)d_in[5];
    const float* w2a = (const float*)d_in[6];
    const float* b2a = (const float*)d_in[7];
    const float* w2b = (const float*)d_in[8];
    const float* b2b = (const float*)d_in[9];
    const float* g1  = (const float*)d_in[10];
    const float* be1 = (const float*)d_in[11];
    const float* m1  = (const float*)d_in[12];
    const float* v1  = (const float*)d_in[13];
    const float* g2  = (const float*)d_in[14];
    const float* be2 = (const float*)d_in[15];
    const float* m2  = (const float*)d_in[16];
    const float* v2  = (const float*)d_in[17];
    const float* f1w = (const float*)d_in[18];
    const float* f1b = (const float*)d_in[19];
    const float* f2w = (const float*)d_in[20];
    const float* f2b = (const float*)d_in[21];
    float* out = (float*)d_out;

    char* ws = (char*)d_ws;
    const size_t EB = (size_t)E_ * 4;        // bytes per E-int array
    const size_t NB = (size_t)N_ * DIM_ * 4; // bytes per node-feature buffer
    int*   flag    = (int*)ws;
    int*   edges32 = (int*)(ws + 256);            // src[E] then dst[E]
    float* y       = (float*)(ws + 256 + 2 * EB);
    float* agg     = (float*)(ws + 256 + 2 * EB + NB);
    float* z       = (float*)(ws + 256 + 2 * EB + 2 * NB);

    detect_kernel<<<1, 64, 0, stream>>>(edg, flag);
    convert_kernel<<<(2 * E_ + 255) / 256, 256, 0, stream>>>(edg, flag, edges32);

    // Layer 1: project (128->32) BEFORE aggregation (linearity of segment_sum)
    proj1_kernel<<<N_ / 32, 256, 0, stream>>>(x, w1a, y);
    hipMemsetAsync(agg, 0, NB, stream);
    agg_kernel<<<(E_ * 8) / 256, 256, 0, stream>>>(edges32, edges32 + E_, y, agg);
    mlp1_kernel<<<N_ / 8, 256, 0, stream>>>(y, agg, b1a, w1b, b1b, g1, be1, m1, v1, w2a, z);

    // Layer 2: aggregate z = bn1(h) @ w2a (w2a folded before aggregation)
    hipMemsetAsync(agg, 0, NB, stream);
    agg_kernel<<<(E_ * 8) / 256, 256, 0, stream>>>(edges32, edges32 + E_, z, agg);
    mlp2_kernel<<<N_ / 8, 256, 0, stream>>>(z, agg, b2a, w2b, b2b, g2, be2, m2, v2,
                                            f1w, f1b, f2w, f2b, out);
}

// Round 2
// 518.376 us; speedup vs baseline: 3.0300x; 3.0300x over previous
//
#include <hip/hip_runtime.h>

// Problem constants
static constexpr int N_   = 100000;
static constexpr int E_   = 1600000;
static constexpr int FIN_ = 128;
static constexpr int DIM_ = 32;
static constexpr int NC_  = 40;

static constexpr int SCAN_CHUNK = 1024;                       // elems per scan block
static constexpr int SCAN_NB    = (N_ + SCAN_CHUNK - 1) / SCAN_CHUNK; // 98

// ---------------------------------------------------------------------------
// Edge dtype detection: reference says int64, but JAX x64-off gives int32.
// int32 buffer read as int64 -> garbage high words -> out of [0,N).
// ---------------------------------------------------------------------------
__global__ void detect_kernel(const void* __restrict__ edge, int* __restrict__ flag) {
    if (blockIdx.x == 0 && threadIdx.x == 0) {
        const long long* p = (const long long*)edge;
        int ok = 1;
        for (int i = 0; i < 64; ++i) {
            long long v = p[i];
            if (v < 0 || v >= (long long)N_) { ok = 0; break; }
        }
        *flag = ok;   // 1 => int64 layout
    }
}

__device__ __forceinline__ int edge_at(const void* e, int is64, long long i) {
    return is64 ? (int)((const long long*)e)[i] : ((const int*)e)[i];
}

// ---------------------------------------------------------------------------
// CSR build step 1: in-degree histogram (int atomics)
// ---------------------------------------------------------------------------
__global__ __launch_bounds__(256) void hist_kernel(const void* __restrict__ edge,
                                                   const int* __restrict__ flag,
                                                   int* __restrict__ deg) {
    int e = blockIdx.x * 256 + threadIdx.x;
    if (e >= E_) return;
    int d = edge_at(edge, *flag, (long long)E_ + e);
    atomicAdd(&deg[d], 1);
}

// ---------------------------------------------------------------------------
// CSR build step 2: exclusive scan of deg[N] -> offs[N+1] (3 kernels)
// ---------------------------------------------------------------------------
__global__ __launch_bounds__(256) void scan1_kernel(const int* __restrict__ deg,
                                                    int* __restrict__ blockSum) {
    __shared__ int wsum[4];
    int b = blockIdx.x;
    int base = b * SCAN_CHUNK + threadIdx.x * 4;
    int s = 0;
#pragma unroll
    for (int j = 0; j < 4; ++j) { int i = base + j; if (i < N_) s += deg[i]; }
#pragma unroll
    for (int off = 32; off; off >>= 1) s += __shfl_down(s, off);
    if ((threadIdx.x & 63) == 0) wsum[threadIdx.x >> 6] = s;
    __syncthreads();
    if (threadIdx.x == 0) blockSum[b] = wsum[0] + wsum[1] + wsum[2] + wsum[3];
}

__global__ void scan2_kernel(const int* __restrict__ blockSum,
                             int* __restrict__ blockBase,
                             int* __restrict__ offs) {
    if (threadIdx.x == 0) {
        int run = 0;
        for (int i = 0; i < SCAN_NB; ++i) { blockBase[i] = run; run += blockSum[i]; }
        offs[N_] = run;   // == E_
    }
}

__global__ __launch_bounds__(256) void scan3_kernel(const int* __restrict__ deg,
                                                    const int* __restrict__ blockBase,
                                                    int* __restrict__ offs,
                                                    int* __restrict__ cursor) {
    __shared__ int wsum[4];
    int b = blockIdx.x;
    int lane = threadIdx.x & 63, wid = threadIdx.x >> 6;
    int base = b * SCAN_CHUNK + threadIdx.x * 4;
    int a[4];
#pragma unroll
    for (int j = 0; j < 4; ++j) { int i = base + j; a[j] = (i < N_) ? deg[i] : 0; }
    int s = a[0] + a[1] + a[2] + a[3];
    int v = s;
#pragma unroll
    for (int off = 1; off < 64; off <<= 1) {
        int u = __shfl_up(v, off);
        if (lane >= off) v += u;
    }
    if (lane == 63) wsum[wid] = v;
    __syncthreads();
    int wbase = 0;
    for (int w = 0; w < wid; ++w) wbase += wsum[w];
    int g = blockBase[b] + wbase + (v - s);   // exclusive prefix for this thread's chunk
#pragma unroll
    for (int j = 0; j < 4; ++j) {
        int i = base + j;
        if (i < N_) { offs[i] = g; cursor[i] = g; }
        g += a[j];
    }
}

// ---------------------------------------------------------------------------
// CSR build step 3: scatter src ids into per-dst buckets
// ---------------------------------------------------------------------------
__global__ __launch_bounds__(256) void scatter_kernel(const void* __restrict__ edge,
                                                      const int* __restrict__ flag,
                                                      int* __restrict__ cursor,
                                                      int* __restrict__ csr) {
    int e = blockIdx.x * 256 + threadIdx.x;
    if (e >= E_) return;
    int f = *flag;
    int s = edge_at(edge, f, e);
    int d = edge_at(edge, f, (long long)E_ + e);
    int pos = atomicAdd(&cursor[d], 1);
    csr[pos] = s;
}

// ---------------------------------------------------------------------------
// y = x @ w1a   (100000x128 @ 128x32). 32 nodes per block, 256 threads.
// ---------------------------------------------------------------------------
__global__ __launch_bounds__(256) void proj1_kernel(const float* __restrict__ x,
                                                    const float* __restrict__ w,
                                                    float* __restrict__ y) {
    __shared__ float wsm[FIN_ * DIM_];   // w[k][d]
    __shared__ float xs[32][FIN_];       // 32 node rows
    int tid = threadIdx.x;

    const float4* w4 = (const float4*)w;
    float4* ws4 = (float4*)wsm;
    for (int i = tid; i < FIN_ * DIM_ / 4; i += 256) ws4[i] = w4[i];

    int nodeBase = blockIdx.x * 32;
    const float4* x4 = (const float4*)(x + (size_t)nodeBase * FIN_);
    float4* xs4 = (float4*)&xs[0][0];
    for (int i = tid; i < 32 * FIN_ / 4; i += 256) xs4[i] = x4[i];
    __syncthreads();

    int d = tid & 31, ns = tid >> 5;     // ns in [0,8)
    for (int rep = 0; rep < 4; ++rep) {
        int node = ns + rep * 8;
        float acc = 0.f;
#pragma unroll 4
        for (int k = 0; k < FIN_; ++k) acc += xs[node][k] * wsm[k * DIM_ + d];
        y[(size_t)(nodeBase + node) * DIM_ + d] = acc;
    }
}

// ---------------------------------------------------------------------------
// Gather aggregation: agg[n] = sum_{e in CSR[n]} vec[src[e]].
// 8 lanes per node (float4 each), 32 nodes per 256-thread block.
// ---------------------------------------------------------------------------
__global__ __launch_bounds__(256) void agg_csr_kernel(const int* __restrict__ offs,
                                                      const int* __restrict__ csr,
                                                      const float* __restrict__ vec,
                                                      float* __restrict__ agg) {
    int lane = threadIdx.x & 7;          // which float4 of the 32-dim row
    int node = blockIdx.x * 32 + (threadIdx.x >> 3);
    if (node >= N_) return;
    int beg = offs[node], end = offs[node + 1];
    float4 acc = make_float4(0.f, 0.f, 0.f, 0.f);
    int i = beg;
    for (; i + 1 < end; i += 2) {        // 2-wide for load-level parallelism
        int s0 = csr[i], s1 = csr[i + 1];
        float4 v0 = ((const float4*)(vec + (size_t)s0 * DIM_))[lane];
        float4 v1 = ((const float4*)(vec + (size_t)s1 * DIM_))[lane];
        acc.x += v0.x + v1.x; acc.y += v0.y + v1.y;
        acc.z += v0.z + v1.z; acc.w += v0.w + v1.w;
    }
    if (i < end) {
        int s0 = csr[i];
        float4 v0 = ((const float4*)(vec + (size_t)s0 * DIM_))[lane];
        acc.x += v0.x; acc.y += v0.y; acc.z += v0.z; acc.w += v0.w;
    }
    ((float4*)(agg + (size_t)node * DIM_))[lane] = acc;
}

// ---------------------------------------------------------------------------
// Node MLP 1: u=relu(agg+y+b1a); h=u@w1b+b1b; hb=bn1(relu(h)); z = hb@w2a.
// ---------------------------------------------------------------------------
__global__ __launch_bounds__(256) void mlp1_kernel(const float* __restrict__ y,
                                                   const float* __restrict__ agg,
                                                   const float* __restrict__ b1a,
                                                   const float* __restrict__ w1b,
                                                   const float* __restrict__ b1b,
                                                   const float* __restrict__ g1,
                                                   const float* __restrict__ be1,
                                                   const float* __restrict__ m1,
                                                   const float* __restrict__ v1,
                                                   const float* __restrict__ w2a,
                                                   float* __restrict__ z) {
    __shared__ float w1s[DIM_ * DIM_];
    __shared__ float w2s[DIM_ * DIM_];
    __shared__ float s[8][DIM_ + 1];
    int tid = threadIdx.x;
    for (int i = tid; i < DIM_ * DIM_; i += 256) { w1s[i] = w1b[i]; w2s[i] = w2a[i]; }

    int d = tid & 31, ns = tid >> 5;
    int node = blockIdx.x * 8 + ns;
    size_t base = (size_t)node * DIM_ + d;

    float sc1 = g1[d] * rsqrtf(v1[d] + 1e-5f);
    float sh1 = be1[d] - m1[d] * sc1;

    float u = fmaxf(agg[base] + y[base] + b1a[d], 0.f);
    s[ns][d] = u;
    __syncthreads();

    float acc = b1b[d];
#pragma unroll
    for (int k = 0; k < DIM_; ++k) acc += s[ns][k] * w1s[k * DIM_ + d];
    float hb = fmaxf(acc, 0.f) * sc1 + sh1;   // relu then bn1
    __syncthreads();
    s[ns][d] = hb;
    __syncthreads();

    float acc2 = 0.f;
#pragma unroll
    for (int k = 0; k < DIM_; ++k) acc2 += s[ns][k] * w2s[k * DIM_ + d];
    z[base] = acc2;
}

// ---------------------------------------------------------------------------
// Node MLP 2 + head: u=relu(agg2+z+b2a); h2=u@w2b+b2b; hb=bn2(h2);
// f=relu(hb@fc1w+fc1b); logits=f@fc2w+fc2b; out=log_softmax(logits).
// ---------------------------------------------------------------------------
__global__ __launch_bounds__(256) void mlp2_kernel(const float* __restrict__ z,
                                                   const float* __restrict__ agg,
                                                   const float* __restrict__ b2a,
                                                   const float* __restrict__ w2b,
                                                   const float* __restrict__ b2b,
                                                   const float* __restrict__ g2,
                                                   const float* __restrict__ be2,
                                                   const float* __restrict__ m2,
                                                   const float* __restrict__ v2,
                                                   const float* __restrict__ f1w,
                                                   const float* __restrict__ f1b,
                                                   const float* __restrict__ f2w,
                                                   const float* __restrict__ f2b,
                                                   float* __restrict__ out) {
    __shared__ float wA[DIM_ * DIM_];
    __shared__ float wB[DIM_ * DIM_];
    __shared__ float wC[DIM_ * NC_];
    __shared__ float s[8][DIM_ + 1];
    int tid = threadIdx.x;
    for (int i = tid; i < DIM_ * DIM_; i += 256) { wA[i] = w2b[i]; wB[i] = f1w[i]; }
    for (int i = tid; i < DIM_ * NC_; i += 256) wC[i] = f2w[i];

    int d = tid & 31, ns = tid >> 5;
    int node = blockIdx.x * 8 + ns;
    size_t base = (size_t)node * DIM_ + d;

    float sc2 = g2[d] * rsqrtf(v2[d] + 1e-5f);
    float sh2 = be2[d] - m2[d] * sc2;

    float u = fmaxf(agg[base] + z[base] + b2a[d], 0.f);
    s[ns][d] = u;
    __syncthreads();

    float acc = b2b[d];
#pragma unroll
    for (int k = 0; k < DIM_; ++k) acc += s[ns][k] * wA[k * DIM_ + d];
    float hb = acc * sc2 + sh2;               // bn2, NO relu between conv2 and bn2
    __syncthreads();
    s[ns][d] = hb;
    __syncthreads();

    float f = f1b[d];
#pragma unroll
    for (int k = 0; k < DIM_; ++k) f += s[ns][k] * wB[k * DIM_ + d];
    f = fmaxf(f, 0.f);
    __syncthreads();
    s[ns][d] = f;
    __syncthreads();

    int c2 = 32 + (d & 7);
    float l0 = f2b[d];
    float l1 = f2b[c2];
#pragma unroll
    for (int k = 0; k < DIM_; ++k) {
        float fv = s[ns][k];
        l0 += fv * wC[k * NC_ + d];
        l1 += fv * wC[k * NC_ + c2];
    }

    float mx = fmaxf(l0, l1);
#pragma unroll
    for (int off = 16; off; off >>= 1) mx = fmaxf(mx, __shfl_xor(mx, off));
    float se = __expf(l0 - mx) + ((d < 8) ? __expf(l1 - mx) : 0.f);
#pragma unroll
    for (int off = 16; off; off >>= 1) se += __shfl_xor(se, off);
    float lse = mx + __logf(se);

    out[(size_t)node * NC_ + d] = l0 - lse;
    if (d < 8) out[(size_t)node * NC_ + 32 + d] = l1 - lse;
}

// ---------------------------------------------------------------------------
extern "C" void kernel_launch(void* const* d_in, const int* in_sizes, int n_in,
                              void* d_out, int out_size, void* d_ws, size_t ws_size,
                              hipStream_t stream) {
    const float* x   = (const float*)d_in[0];
    const void*  edg = d_in[1];
    const float* w1a = (const float*)d_in[2];
    const float* b1a = (const float*)d_in[3];
    const float* w1b = (const float*)d_in[4];
    const float* b1b = (const float*)d_in[5];
    const float* w2a = (const float*)d_in[6];
    const float* b2a = (const float*)d_in[7];
    const float* w2b = (const float*)d_in[8];
    const float* b2b = (const float*)d_in[9];
    const float* g1  = (const float*)d_in[10];
    const float* be1 = (const float*)d_in[11];
    const float* m1  = (const float*)d_in[12];
    const float* v1  = (const float*)d_in[13];
    const float* g2  = (const float*)d_in[14];
    const float* be2 = (const float*)d_in[15];
    const float* m2  = (const float*)d_in[16];
    const float* v2  = (const float*)d_in[17];
    const float* f1w = (const float*)d_in[18];
    const float* f1b = (const float*)d_in[19];
    const float* f2w = (const float*)d_in[20];
    const float* f2b = (const float*)d_in[21];
    float* out = (float*)d_out;

    // Workspace layout (all 256B aligned)
    char* ws = (char*)d_ws;
    const size_t NB = (size_t)N_ * DIM_ * 4;   // node-feature buffer bytes
    int*   flag      = (int*)ws;                       // 256 B
    int*   deg       = (int*)(ws + 256);               // N ints
    int*   offs      = (int*)(ws + 256 + 400256);      // N+1 ints
    int*   cursor    = (int*)(ws + 256 + 800768);      // N ints
    int*   blockSum  = (int*)(ws + 256 + 1200768);     // SCAN_NB ints
    int*   blockBase = (int*)(ws + 256 + 1201792);     // SCAN_NB ints
    int*   csr       = (int*)(ws + 256 + 1202816);     // E ints
    float* y         = (float*)(ws + 256 + 1202816 + 6400000);
    float* agg       = (float*)(ws + 256 + 1202816 + 6400000 + NB);
    float* z         = (float*)(ws + 256 + 1202816 + 6400000 + 2 * NB);

    detect_kernel<<<1, 64, 0, stream>>>(edg, flag);

    // ---- Build CSR (reused by both layers) ----
    hipMemsetAsync(deg, 0, (size_t)N_ * 4, stream);
    hist_kernel<<<(E_ + 255) / 256, 256, 0, stream>>>(edg, flag, deg);
    scan1_kernel<<<SCAN_NB, 256, 0, stream>>>(deg, blockSum);
    scan2_kernel<<<1, 64, 0, stream>>>(blockSum, blockBase, offs);
    scan3_kernel<<<SCAN_NB, 256, 0, stream>>>(deg, blockBase, offs, cursor);
    scatter_kernel<<<(E_ + 255) / 256, 256, 0, stream>>>(edg, flag, cursor, csr);

    // ---- Layer 1: project 128->32 BEFORE aggregation (linearity) ----
    proj1_kernel<<<N_ / 32, 256, 0, stream>>>(x, w1a, y);
    agg_csr_kernel<<<(N_ + 31) / 32, 256, 0, stream>>>(offs, csr, y, agg);
    mlp1_kernel<<<N_ / 8, 256, 0, stream>>>(y, agg, b1a, w1b, b1b, g1, be1, m1, v1, w2a, z);

    // ---- Layer 2: aggregate z = bn1(h) @ w2a (w2a folded pre-aggregation) ----
    agg_csr_kernel<<<(N_ + 31) / 32, 256, 0, stream>>>(offs, csr, z, agg);
    mlp2_kernel<<<N_ / 8, 256, 0, stream>>>(z, agg, b2a, w2b, b2b, g2, be2, m2, v2,
                                            f1w, f1b, f2w, f2b, out);
}